// Round 4
// baseline (223.751 us; speedup 1.0000x reference)
//
#include <hip/hip_runtime.h>
#include <hip/hip_bf16.h>
#include <stdint.h>

#define BATCH 2
#define HEADS 16
#define BH    32
#define SEQ   2048
#define DIM   128
#define ELEMS (BATCH*HEADS*SEQ*DIM)   // 8388608 per tensor

#define KVB   64
#define NT    (SEQ/KVB)               // 32 tiles

using f32x4  = __attribute__((ext_vector_type(4))) float;
using f32x16 = __attribute__((ext_vector_type(16))) float;
using bf16x8 = __attribute__((ext_vector_type(8))) short;
using us4    = __attribute__((ext_vector_type(4))) unsigned short;

__device__ __forceinline__ unsigned short f2bf(float f) {
    union { float f; uint32_t u; } v; v.f = f;
    uint32_t u = v.u;
    uint32_t r = u + 0x7FFFu + ((u >> 16) & 1u);   // RNE
    return (unsigned short)(r >> 16);
}

__device__ __forceinline__ uint32_t packbf2(float lo, float hi) {
    __hip_bfloat162 h2 = __float22bfloat162_rn(make_float2(lo, hi));
    union { __hip_bfloat162 h; uint32_t u; } c; c.h = h2;
    return c.u;   // low16 = lo, high16 = hi
}

// ---- fused prep ----
// blocks [0,2048):    Q fp32 -> bf16, pre-scaled by 1/sqrt(d)*log2(e)
// blocks [2048,4096): K fp32 -> bf16
// blocks [4096,6144): V fp32 [bh][n][d] -> VT bf16 [bh][d][n]
__global__ __launch_bounds__(256) void prep(const float* __restrict__ Q,
                                            const float* __restrict__ K,
                                            const float* __restrict__ V,
                                            unsigned short* __restrict__ qb,
                                            unsigned short* __restrict__ kb,
                                            unsigned short* __restrict__ vt) {
    const int b = blockIdx.x, t = threadIdx.x;
    const float scl = 0.08838834764831845f * 1.4426950408889634f;
    if (b < 4096) {
        const bool isQ = b < 2048;
        const float* src = isQ ? Q : K;
        unsigned short* dst = isQ ? qb : kb;
        const float f = isQ ? scl : 1.0f;
        size_t base = (size_t)(isQ ? b : b - 2048) * 4096 + t * 4;
        #pragma unroll
        for (int j = 0; j < 4; ++j) {
            f32x4 v = *(const f32x4*)(src + base + j * 1024);
            us4 o;
            #pragma unroll
            for (int jj = 0; jj < 4; ++jj) o[jj] = f2bf(v[jj] * f);
            *(us4*)(dst + base + j * 1024) = o;
        }
    } else {
        __shared__ unsigned short tile[64][66];
        const int b2 = b - 4096;
        const int bh = b2 >> 6, rem = b2 & 63;
        const int n0 = (rem >> 1) * 64, d0 = (rem & 1) * 64;
        const int rr = t >> 4, cc = t & 15;
        #pragma unroll
        for (int j = 0; j < 4; ++j) {
            int row = rr + 16 * j;
            f32x4 v = *(const f32x4*)(V + ((size_t)bh * SEQ + n0 + row) * DIM + d0 + cc * 4);
            #pragma unroll
            for (int jj = 0; jj < 4; ++jj) tile[row][cc * 4 + jj] = f2bf(v[jj]);
        }
        __syncthreads();
        #pragma unroll
        for (int j = 0; j < 4; ++j) {
            int drow = rr + 16 * j;
            us4 o;
            #pragma unroll
            for (int jj = 0; jj < 4; ++jj) o[jj] = tile[cc * 4 + jj][drow];
            *(us4*)(vt + ((size_t)bh * DIM + d0 + drow) * SEQ + n0 + cc * 4) = o;
        }
    }
}

// ---- flash attention: 4 waves x QBLK=32, KVBLK=64, 32x32x16 MFMA ----
__global__ __launch_bounds__(256, 2) void attn_fwd(const unsigned short* __restrict__ Qb,
                                                   const unsigned short* __restrict__ Kb,
                                                   const unsigned short* __restrict__ VTb,
                                                   float* __restrict__ Out) {
    __shared__ __attribute__((aligned(16))) char smem[65536];

    const int head = blockIdx.y;
    const int wid  = threadIdx.x >> 6;
    const int lane = threadIdx.x & 63;
    const int l31  = lane & 31;
    const int hL   = lane >> 5;
    const int q0   = blockIdx.x * 128 + wid * 32;

    const unsigned short* Qh = Qb + (size_t)head * SEQ * DIM;
    const char* KhB  = (const char*)(Kb  + (size_t)head * SEQ * DIM);
    const char* VThB = (const char*)(VTb + (size_t)head * DIM * SEQ);

    // Q B-frags (bf16, pre-scaled in prep): lane holds Q[q0+l31][16u + 8hL .. +7]
    bf16x8 qf[8];
    {
        const char* qrow = (const char*)(Qh + (size_t)(q0 + l31) * DIM) + 16 * hL;
        #pragma unroll
        for (int u = 0; u < 8; ++u) qf[u] = *(const bf16x8*)(qrow + 32 * u);
    }

    f32x16 acc[4];
    #pragma unroll
    for (int m = 0; m < 4; ++m) acc[m] = (f32x16)(0.f);
    float m_run = -INFINITY, l_run = 0.f;

    const int swzK = (l31 & 15) << 4;          // K read swizzle
    const int swzV = ((l31 >> 1) & 7) << 4;    // VT read swizzle (row-pair)

    auto STAGE = [&](int buf, int kv0) {
        #pragma unroll
        for (int i = 0; i < 4; ++i) {
            int seg = wid * 4 + i;
            int r   = seg * 4 + (lane >> 4);
            int cb  = ((lane & 15) << 4) ^ ((r & 15) << 4);
            const char* g = KhB + (((size_t)(kv0 + r)) << 8) + cb;
            __builtin_amdgcn_global_load_lds(
                (const __attribute__((address_space(1))) void*)g,
                (__attribute__((address_space(3))) void*)(smem + buf * 16384 + seg * 1024),
                16, 0, 0);
        }
        #pragma unroll
        for (int i = 0; i < 4; ++i) {
            int seg = wid * 4 + i;
            int rp  = seg * 4 + (lane >> 4);          // row-pair 0..63
            int q8  = (lane & 15) << 4;
            int pre = q8 ^ ((rp & 7) << 4);
            int r   = 2 * rp + (pre >> 7);            // VT d-row 0..127
            int cb  = pre & 127;
            const char* g = VThB + (size_t)r * (SEQ * 2) + ((size_t)kv0 << 1) + cb;
            __builtin_amdgcn_global_load_lds(
                (const __attribute__((address_space(1))) void*)g,
                (__attribute__((address_space(3))) void*)(smem + 32768 + buf * 16384 + seg * 1024),
                16, 0, 0);
        }
    };

    STAGE(0, 0);

    for (int t = 0; t < NT; ++t) {
        const int cur = t & 1;
        if (t + 1 < NT) {
            STAGE(cur ^ 1, (t + 1) * KVB);
            asm volatile("s_waitcnt vmcnt(8)" ::: "memory");
        } else {
            asm volatile("s_waitcnt vmcnt(0)" ::: "memory");
        }
        __builtin_amdgcn_s_barrier();
        asm volatile("" ::: "memory");

        const char* kb = smem + cur * 16384;
        const char* vb = smem + 32768 + cur * 16384;

        // ---- QK^T: S^T[kv][q] (scale pre-folded into Q) ----
        f32x16 s0 = (f32x16)(0.f), s1 = (f32x16)(0.f);
        __builtin_amdgcn_s_setprio(1);
        {
            const char* krow0 = kb + (size_t)l31 * 256;
            const char* krow1 = kb + (size_t)(32 + l31) * 256;
            #pragma unroll
            for (int u = 0; u < 8; ++u) {
                int cb = (32 * u + 16 * hL) ^ swzK;
                bf16x8 k0 = *(const bf16x8*)(krow0 + cb);
                bf16x8 k1 = *(const bf16x8*)(krow1 + cb);
                s0 = __builtin_amdgcn_mfma_f32_32x32x16_bf16(k0, qf[u], s0, 0, 0, 0);
                s1 = __builtin_amdgcn_mfma_f32_32x32x16_bf16(k1, qf[u], s1, 0, 0, 0);
            }
        }
        __builtin_amdgcn_s_setprio(0);

        // ---- online softmax ----
        float smax = -1e30f;
        #pragma unroll
        for (int r = 0; r < 16; ++r)
            smax = fmaxf(smax, fmaxf(s0[r], s1[r]));
        smax = fmaxf(smax, __shfl_xor(smax, 32));

        if (!__all(smax - m_run <= 8.f)) {          // defer-max (T13)
            float mnew = fmaxf(m_run, smax);
            float corr = __builtin_amdgcn_exp2f(m_run - mnew);
            #pragma unroll
            for (int m = 0; m < 4; ++m) acc[m] *= corr;
            l_run *= corr;
            m_run = mnew;
        }

        float psum = 0.f;
        #pragma unroll
        for (int r = 0; r < 16; ++r) {
            s0[r] = __builtin_amdgcn_exp2f(s0[r] - m_run);
            s1[r] = __builtin_amdgcn_exp2f(s1[r] - m_run);
            psum += s0[r] + s1[r];
        }
        l_run += psum;   // lane-local; pair-reduced in epilogue

        // ---- pack P to bf16 dword pairs ----
        uint32_t w0[8], w1[8];
        #pragma unroll
        for (int k2 = 0; k2 < 8; ++k2) {
            w0[k2] = packbf2(s0[2 * k2], s0[2 * k2 + 1]);
            w1[k2] = packbf2(s1[2 * k2], s1[2 * k2 + 1]);
        }

        // ---- PV: O^T[d][q] += V^T * P^T (V reads inline — r3 hoist regressed) ----
        __builtin_amdgcn_s_setprio(1);
        #pragma unroll
        for (int tt = 0; tt < 2; ++tt) {
            #pragma unroll
            for (int ssi = 0; ssi < 2; ++ssi) {
                uint32_t A0 = tt ? w1[4 * ssi]     : w0[4 * ssi];
                uint32_t A1 = tt ? w1[4 * ssi + 1] : w0[4 * ssi + 1];
                uint32_t C0 = tt ? w1[4 * ssi + 2] : w0[4 * ssi + 2];
                uint32_t C1 = tt ? w1[4 * ssi + 3] : w0[4 * ssi + 3];
                uint32_t o0 = hL ? A0 : C0;
                uint32_t o1 = hL ? A1 : C1;
                uint32_t e0 = (uint32_t)__shfl_xor((int)o0, 32);
                uint32_t e1 = (uint32_t)__shfl_xor((int)o1, 32);
                union { uint32_t u[4]; bf16x8 v; } Bf;
                Bf.u[0] = hL ? e0 : A0;
                Bf.u[1] = hL ? e1 : A1;
                Bf.u[2] = hL ? C0 : e0;
                Bf.u[3] = hL ? C1 : e1;
                const int cbv = (32 * (2 * tt + ssi) + 16 * hL) + ((l31 & 1) << 7);
                #pragma unroll
                for (int m = 0; m < 4; ++m) {
                    int rp = 16 * m + (l31 >> 1);
                    bf16x8 vf = *(const bf16x8*)(vb + (size_t)rp * 256 + (cbv ^ swzV));
                    acc[m] = __builtin_amdgcn_mfma_f32_32x32x16_bf16(vf, Bf.v, acc[m], 0, 0, 0);
                }
            }
        }
        __builtin_amdgcn_s_setprio(0);

        asm volatile("" ::: "memory");
        __builtin_amdgcn_s_barrier();
    }

    // ---- epilogue: normalize, swizzled LDS transpose, coalesced stores ----
    __syncthreads();
    const float l_tot = l_run + __shfl_xor(l_run, 32);
    const float inv = 1.0f / l_tot;
    float* ob = (float*)(smem + wid * 16384);
    #pragma unroll
    for (int m = 0; m < 4; ++m) {
        #pragma unroll
        for (int r = 0; r < 16; ++r) {
            int d = 32 * m + (r & 3) + 8 * (r >> 2) + 4 * hL;
            ob[l31 * 128 + (d ^ ((l31 & 7) << 2))] = acc[m][r] * inv;
        }
    }
    __syncthreads();
    {
        float* outp = Out + ((size_t)head * SEQ + q0) * DIM;
        #pragma unroll
        for (int i = 0; i < 16; ++i) {
            int row = 2 * i + hL;
            f32x4 v = *(const f32x4*)(ob + row * 128 + ((4 * l31) ^ ((row & 7) << 2)));
            *(f32x4*)(outp + (size_t)row * DIM + 4 * l31) = v;
        }
    }
}

extern "C" void kernel_launch(void* const* d_in, const int* in_sizes, int n_in,
                              void* d_out, int out_size, void* d_ws, size_t ws_size,
                              hipStream_t stream) {
    (void)in_sizes; (void)n_in; (void)out_size;
    const float* q = (const float*)d_in[0];
    const float* k = (const float*)d_in[1];
    const float* v = (const float*)d_in[2];
    float* out = (float*)d_out;

    const size_t needed = (size_t)ELEMS * 2 * 3;
    if (ws_size < needed) return;

    unsigned short* qb = (unsigned short*)d_ws;
    unsigned short* kb = qb + ELEMS;
    unsigned short* vt = kb + ELEMS;

    prep<<<6144, 256, 0, stream>>>(q, k, v, qb, kb, vt);
    attn_fwd<<<dim3(SEQ / 128, BH), 256, 0, stream>>>(qb, kb, vt, out);
}

// Round 5
// 219.160 us; speedup vs baseline: 1.0209x; 1.0209x over previous
//
#include <hip/hip_runtime.h>
#include <hip/hip_bf16.h>
#include <stdint.h>

#define BATCH 2
#define HEADS 16
#define BH    32
#define SEQ   2048
#define DIM   128
#define ELEMS (BATCH*HEADS*SEQ*DIM)   // 8388608 per tensor

#define KVB   64
#define NT    (SEQ/KVB)               // 32 tiles

using f32x4  = __attribute__((ext_vector_type(4))) float;
using f32x16 = __attribute__((ext_vector_type(16))) float;
using bf16x8 = __attribute__((ext_vector_type(8))) short;
using us4    = __attribute__((ext_vector_type(4))) unsigned short;

__device__ __forceinline__ unsigned short f2bf(float f) {
    union { float f; uint32_t u; } v; v.f = f;
    uint32_t u = v.u;
    uint32_t r = u + 0x7FFFu + ((u >> 16) & 1u);   // RNE
    return (unsigned short)(r >> 16);
}

__device__ __forceinline__ uint32_t packbf2(float lo, float hi) {
    __hip_bfloat162 h2 = __float22bfloat162_rn(make_float2(lo, hi));
    union { __hip_bfloat162 h; uint32_t u; } c; c.h = h2;
    return c.u;   // low16 = lo, high16 = hi
}

// ---- fused prep ----
// blocks [0,2048):    Q fp32 -> bf16, pre-scaled by 1/sqrt(d)*log2(e)
// blocks [2048,4096): K fp32 -> bf16
// blocks [4096,6144): V fp32 [bh][n][d] -> VT bf16 [bh][d][n]
__global__ __launch_bounds__(256) void prep(const float* __restrict__ Q,
                                            const float* __restrict__ K,
                                            const float* __restrict__ V,
                                            unsigned short* __restrict__ qb,
                                            unsigned short* __restrict__ kb,
                                            unsigned short* __restrict__ vt) {
    const int b = blockIdx.x, t = threadIdx.x;
    const float scl = 0.08838834764831845f * 1.4426950408889634f;
    if (b < 4096) {
        const bool isQ = b < 2048;
        const float* src = isQ ? Q : K;
        unsigned short* dst = isQ ? qb : kb;
        const float f = isQ ? scl : 1.0f;
        size_t base = (size_t)(isQ ? b : b - 2048) * 4096 + t * 4;
        #pragma unroll
        for (int j = 0; j < 4; ++j) {
            f32x4 v = *(const f32x4*)(src + base + j * 1024);
            us4 o;
            #pragma unroll
            for (int jj = 0; jj < 4; ++jj) o[jj] = f2bf(v[jj] * f);
            *(us4*)(dst + base + j * 1024) = o;
        }
    } else {
        __shared__ unsigned short tile[64][66];
        const int b2 = b - 4096;
        const int bh = b2 >> 6, rem = b2 & 63;
        const int n0 = (rem >> 1) * 64, d0 = (rem & 1) * 64;
        const int rr = t >> 4, cc = t & 15;
        #pragma unroll
        for (int j = 0; j < 4; ++j) {
            int row = rr + 16 * j;
            f32x4 v = *(const f32x4*)(V + ((size_t)bh * SEQ + n0 + row) * DIM + d0 + cc * 4);
            #pragma unroll
            for (int jj = 0; jj < 4; ++jj) tile[row][cc * 4 + jj] = f2bf(v[jj]);
        }
        __syncthreads();
        #pragma unroll
        for (int j = 0; j < 4; ++j) {
            int drow = rr + 16 * j;
            us4 o;
            #pragma unroll
            for (int jj = 0; jj < 4; ++jj) o[jj] = tile[cc * 4 + jj][drow];
            *(us4*)(vt + ((size_t)bh * DIM + d0 + drow) * SEQ + n0 + cc * 4) = o;
        }
    }
}

// ---- flash attention: 4 waves x QBLK=32, KVBLK=64, 32x32x16 MFMA ----
// 1-D grid of 512, XCD-grouped: each XCD owns 4 complete heads (K/V L2-resident).
__global__ __launch_bounds__(256, 2) void attn_fwd(const unsigned short* __restrict__ Qb,
                                                   const unsigned short* __restrict__ Kb,
                                                   const unsigned short* __restrict__ VTb,
                                                   float* __restrict__ Out) {
    __shared__ __attribute__((aligned(16))) char smem[65536];

    const int bid  = blockIdx.x;
    const int xcd  = bid & 7;
    const int slot = bid >> 3;
    const int head = xcd * 4 + (slot >> 4);    // bijective: 512 = 8 XCD x 4 heads x 16 qtiles
    const int wid  = threadIdx.x >> 6;
    const int lane = threadIdx.x & 63;
    const int l31  = lane & 31;
    const int hL   = lane >> 5;
    const int q0   = (slot & 15) * 128 + wid * 32;

    const unsigned short* Qh = Qb + (size_t)head * SEQ * DIM;
    const char* KhB  = (const char*)(Kb  + (size_t)head * SEQ * DIM);
    const char* VThB = (const char*)(VTb + (size_t)head * DIM * SEQ);

    // Q B-frags (bf16, pre-scaled in prep): lane holds Q[q0+l31][16u + 8hL .. +7]
    bf16x8 qf[8];
    {
        const char* qrow = (const char*)(Qh + (size_t)(q0 + l31) * DIM) + 16 * hL;
        #pragma unroll
        for (int u = 0; u < 8; ++u) qf[u] = *(const bf16x8*)(qrow + 32 * u);
    }

    f32x16 acc[4];
    #pragma unroll
    for (int m = 0; m < 4; ++m) acc[m] = (f32x16)(0.f);
    float m_run = -INFINITY, l_run = 0.f;

    const int swzK = (l31 & 15) << 4;          // K read swizzle
    const int swzV = ((l31 >> 1) & 7) << 4;    // VT read swizzle (row-pair)

    auto STAGE = [&](int buf, int kv0) {
        #pragma unroll
        for (int i = 0; i < 4; ++i) {
            int seg = wid * 4 + i;
            int r   = seg * 4 + (lane >> 4);
            int cb  = ((lane & 15) << 4) ^ ((r & 15) << 4);
            const char* g = KhB + (((size_t)(kv0 + r)) << 8) + cb;
            __builtin_amdgcn_global_load_lds(
                (const __attribute__((address_space(1))) void*)g,
                (__attribute__((address_space(3))) void*)(smem + buf * 16384 + seg * 1024),
                16, 0, 0);
        }
        #pragma unroll
        for (int i = 0; i < 4; ++i) {
            int seg = wid * 4 + i;
            int rp  = seg * 4 + (lane >> 4);          // row-pair 0..63
            int q8  = (lane & 15) << 4;
            int pre = q8 ^ ((rp & 7) << 4);
            int r   = 2 * rp + (pre >> 7);            // VT d-row 0..127
            int cb  = pre & 127;
            const char* g = VThB + (size_t)r * (SEQ * 2) + ((size_t)kv0 << 1) + cb;
            __builtin_amdgcn_global_load_lds(
                (const __attribute__((address_space(1))) void*)g,
                (__attribute__((address_space(3))) void*)(smem + 32768 + buf * 16384 + seg * 1024),
                16, 0, 0);
        }
    };

    STAGE(0, 0);

    for (int t = 0; t < NT; ++t) {
        const int cur = t & 1;
        if (t + 1 < NT) {
            STAGE(cur ^ 1, (t + 1) * KVB);
            asm volatile("s_waitcnt vmcnt(8)" ::: "memory");
        } else {
            asm volatile("s_waitcnt vmcnt(0)" ::: "memory");
        }
        __builtin_amdgcn_s_barrier();
        asm volatile("" ::: "memory");

        const char* kb = smem + cur * 16384;
        const char* vb = smem + 32768 + cur * 16384;

        // ---- QK^T: S^T[kv][q] (scale pre-folded into Q) ----
        f32x16 s0 = (f32x16)(0.f), s1 = (f32x16)(0.f);
        {
            const char* krow0 = kb + (size_t)l31 * 256;
            const char* krow1 = kb + (size_t)(32 + l31) * 256;
            #pragma unroll
            for (int u = 0; u < 8; ++u) {
                int cb = (32 * u + 16 * hL) ^ swzK;
                bf16x8 k0 = *(const bf16x8*)(krow0 + cb);
                bf16x8 k1 = *(const bf16x8*)(krow1 + cb);
                s0 = __builtin_amdgcn_mfma_f32_32x32x16_bf16(k0, qf[u], s0, 0, 0, 0);
                s1 = __builtin_amdgcn_mfma_f32_32x32x16_bf16(k1, qf[u], s1, 0, 0, 0);
            }
        }

        // ---- online softmax ----
        float smax = -1e30f;
        #pragma unroll
        for (int r = 0; r < 16; ++r)
            smax = fmaxf(smax, fmaxf(s0[r], s1[r]));
        smax = fmaxf(smax, __shfl_xor(smax, 32));

        if (!__all(smax - m_run <= 8.f)) {          // defer-max (T13)
            float mnew = fmaxf(m_run, smax);
            float corr = __builtin_amdgcn_exp2f(m_run - mnew);
            #pragma unroll
            for (int m = 0; m < 4; ++m) acc[m] *= corr;
            l_run *= corr;
            m_run = mnew;
        }

        float psum = 0.f;
        #pragma unroll
        for (int r = 0; r < 16; ++r) {
            s0[r] = __builtin_amdgcn_exp2f(s0[r] - m_run);
            s1[r] = __builtin_amdgcn_exp2f(s1[r] - m_run);
            psum += s0[r] + s1[r];
        }
        l_run += psum;   // lane-local; pair-reduced in epilogue

        // ---- pack P to bf16 dword pairs ----
        uint32_t w0[8], w1[8];
        #pragma unroll
        for (int k2 = 0; k2 < 8; ++k2) {
            w0[k2] = packbf2(s0[2 * k2], s0[2 * k2 + 1]);
            w1[k2] = packbf2(s1[2 * k2], s1[2 * k2 + 1]);
        }

        // ---- PV: O^T[d][q] += V^T * P^T (V reads inline) ----
        #pragma unroll
        for (int tt = 0; tt < 2; ++tt) {
            #pragma unroll
            for (int ssi = 0; ssi < 2; ++ssi) {
                uint32_t A0 = tt ? w1[4 * ssi]     : w0[4 * ssi];
                uint32_t A1 = tt ? w1[4 * ssi + 1] : w0[4 * ssi + 1];
                uint32_t C0 = tt ? w1[4 * ssi + 2] : w0[4 * ssi + 2];
                uint32_t C1 = tt ? w1[4 * ssi + 3] : w0[4 * ssi + 3];
                uint32_t o0 = hL ? A0 : C0;
                uint32_t o1 = hL ? A1 : C1;
                uint32_t e0 = (uint32_t)__shfl_xor((int)o0, 32);
                uint32_t e1 = (uint32_t)__shfl_xor((int)o1, 32);
                union { uint32_t u[4]; bf16x8 v; } Bf;
                Bf.u[0] = hL ? e0 : A0;
                Bf.u[1] = hL ? e1 : A1;
                Bf.u[2] = hL ? C0 : e0;
                Bf.u[3] = hL ? C1 : e1;
                const int cbv = (32 * (2 * tt + ssi) + 16 * hL) + ((l31 & 1) << 7);
                #pragma unroll
                for (int m = 0; m < 4; ++m) {
                    int rp = 16 * m + (l31 >> 1);
                    bf16x8 vf = *(const bf16x8*)(vb + (size_t)rp * 256 + (cbv ^ swzV));
                    acc[m] = __builtin_amdgcn_mfma_f32_32x32x16_bf16(vf, Bf.v, acc[m], 0, 0, 0);
                }
            }
        }

        asm volatile("" ::: "memory");
        __builtin_amdgcn_s_barrier();
    }

    // ---- epilogue: normalize, swizzled LDS transpose, coalesced stores ----
    __syncthreads();
    const float l_tot = l_run + __shfl_xor(l_run, 32);
    const float inv = 1.0f / l_tot;
    float* ob = (float*)(smem + wid * 16384);
    #pragma unroll
    for (int m = 0; m < 4; ++m) {
        #pragma unroll
        for (int r = 0; r < 16; ++r) {
            int d = 32 * m + (r & 3) + 8 * (r >> 2) + 4 * hL;
            ob[l31 * 128 + (d ^ ((l31 & 7) << 2))] = acc[m][r] * inv;
        }
    }
    __syncthreads();
    {
        float* outp = Out + ((size_t)head * SEQ + q0) * DIM;
        #pragma unroll
        for (int i = 0; i < 16; ++i) {
            int row = 2 * i + hL;
            f32x4 v = *(const f32x4*)(ob + row * 128 + ((4 * l31) ^ ((row & 7) << 2)));
            *(f32x4*)(outp + (size_t)row * DIM + 4 * l31) = v;
        }
    }
}

extern "C" void kernel_launch(void* const* d_in, const int* in_sizes, int n_in,
                              void* d_out, int out_size, void* d_ws, size_t ws_size,
                              hipStream_t stream) {
    (void)in_sizes; (void)n_in; (void)out_size;
    const float* q = (const float*)d_in[0];
    const float* k = (const float*)d_in[1];
    const float* v = (const float*)d_in[2];
    float* out = (float*)d_out;

    const size_t needed = (size_t)ELEMS * 2 * 3;
    if (ws_size < needed) return;

    unsigned short* qb = (unsigned short*)d_ws;
    unsigned short* kb = qb + ELEMS;
    unsigned short* vt = kb + ELEMS;

    prep<<<6144, 256, 0, stream>>>(q, k, v, qb, kb, vt);
    attn_fwd<<<512, 256, 0, stream>>>(qb, kb, vt, out);
}

// Round 8
// 218.659 us; speedup vs baseline: 1.0233x; 1.0023x over previous
//
#include <hip/hip_runtime.h>
#include <hip/hip_bf16.h>
#include <stdint.h>

#define BATCH 2
#define HEADS 16
#define BH    32
#define SEQ   2048
#define DIM   128
#define ELEMS (BATCH*HEADS*SEQ*DIM)   // 8388608 per tensor

#define KVB   64
#define NT    (SEQ/KVB)               // 32 tiles

using f32x4  = __attribute__((ext_vector_type(4))) float;
using f32x16 = __attribute__((ext_vector_type(16))) float;
using bf16x8 = __attribute__((ext_vector_type(8))) short;
using us4    = __attribute__((ext_vector_type(4))) unsigned short;

__device__ __forceinline__ unsigned short f2bf(float f) {
    union { float f; uint32_t u; } v; v.f = f;
    uint32_t u = v.u;
    uint32_t r = u + 0x7FFFu + ((u >> 16) & 1u);   // RNE
    return (unsigned short)(r >> 16);
}

__device__ __forceinline__ uint32_t packbf2(float lo, float hi) {
    __hip_bfloat162 h2 = __float22bfloat162_rn(make_float2(lo, hi));
    union { __hip_bfloat162 h; uint32_t u; } c; c.h = h2;
    return c.u;   // low16 = lo, high16 = hi
}

// ---- fused prep ----
// blocks [0,2048):    Q fp32 -> bf16, pre-scaled by 1/sqrt(d)*log2(e)
// blocks [2048,4096): K fp32 -> bf16
// blocks [4096,6144): V fp32 [bh][n][d] -> VT bf16 [bh][d][n]
__global__ __launch_bounds__(256) void prep(const float* __restrict__ Q,
                                            const float* __restrict__ K,
                                            const float* __restrict__ V,
                                            unsigned short* __restrict__ qb,
                                            unsigned short* __restrict__ kb,
                                            unsigned short* __restrict__ vt) {
    const int b = blockIdx.x, t = threadIdx.x;
    const float scl = 0.08838834764831845f * 1.4426950408889634f;
    if (b < 4096) {
        const bool isQ = b < 2048;
        const float* src = isQ ? Q : K;
        unsigned short* dst = isQ ? qb : kb;
        const float f = isQ ? scl : 1.0f;
        size_t base = (size_t)(isQ ? b : b - 2048) * 4096 + t * 4;
        #pragma unroll
        for (int j = 0; j < 4; ++j) {
            f32x4 v = *(const f32x4*)(src + base + j * 1024);
            us4 o;
            #pragma unroll
            for (int jj = 0; jj < 4; ++jj) o[jj] = f2bf(v[jj] * f);
            *(us4*)(dst + base + j * 1024) = o;
        }
    } else {
        __shared__ unsigned short tile[64][66];
        const int b2 = b - 4096;
        const int bh = b2 >> 6, rem = b2 & 63;
        const int n0 = (rem >> 1) * 64, d0 = (rem & 1) * 64;
        const int rr = t >> 4, cc = t & 15;
        #pragma unroll
        for (int j = 0; j < 4; ++j) {
            int row = rr + 16 * j;
            f32x4 v = *(const f32x4*)(V + ((size_t)bh * SEQ + n0 + row) * DIM + d0 + cc * 4);
            #pragma unroll
            for (int jj = 0; jj < 4; ++jj) tile[row][cc * 4 + jj] = f2bf(v[jj]);
        }
        __syncthreads();
        #pragma unroll
        for (int j = 0; j < 4; ++j) {
            int drow = rr + 16 * j;
            us4 o;
            #pragma unroll
            for (int jj = 0; jj < 4; ++jj) o[jj] = tile[cc * 4 + jj][drow];
            *(us4*)(vt + ((size_t)bh * DIM + d0 + drow) * SEQ + n0 + cc * 4) = o;
        }
    }
}

// ---- flash attention: 4 waves x QBLK=32, KVBLK=64, 32x32x16 MFMA ----
// Pipelined: QK^T(t+1) MFMA overlaps softmax(t) VALU.
// Staging: K(t+2) issued at phase START (kb[t&1] free after entry barrier),
// V(t+2) at phase END (vb[t&1] free after end barrier) -> both have a full
// phase to land. Per-wave issue order: V(t), K(t+1), V(t+1) outstanding at
// entry (12); vmcnt(4) drains exactly {V(t), K(t+1)} = what this phase reads.
__global__ __launch_bounds__(256, 2) void attn_fwd(const unsigned short* __restrict__ Qb,
                                                   const unsigned short* __restrict__ Kb,
                                                   const unsigned short* __restrict__ VTb,
                                                   float* __restrict__ Out) {
    __shared__ __attribute__((aligned(16))) char smem[65536];

    const int bid  = blockIdx.x;
    const int xcd  = bid & 7;
    const int slot = bid >> 3;
    const int head = xcd * 4 + (slot >> 4);    // bijective: 512 = 8 XCD x 4 heads x 16 qtiles
    const int wid  = threadIdx.x >> 6;
    const int lane = threadIdx.x & 63;
    const int l31  = lane & 31;
    const int hL   = lane >> 5;
    const int q0   = (slot & 15) * 128 + wid * 32;

    const unsigned short* Qh = Qb + (size_t)head * SEQ * DIM;
    const char* KhB  = (const char*)(Kb  + (size_t)head * SEQ * DIM);
    const char* VThB = (const char*)(VTb + (size_t)head * DIM * SEQ);

    // Q B-frags (bf16, pre-scaled in prep): lane holds Q[q0+l31][16u + 8hL .. +7]
    bf16x8 qf[8];
    {
        const char* qrow = (const char*)(Qh + (size_t)(q0 + l31) * DIM) + 16 * hL;
        #pragma unroll
        for (int u = 0; u < 8; ++u) qf[u] = *(const bf16x8*)(qrow + 32 * u);
    }

    f32x16 acc[4];
    #pragma unroll
    for (int m = 0; m < 4; ++m) acc[m] = (f32x16)(0.f);
    float m_run = -INFINITY, l_run = 0.f;

    const int swzK = (l31 & 15) << 4;          // K read swizzle
    const int swzV = ((l31 >> 1) & 7) << 4;    // VT read swizzle (row-pair)

    auto STAGE_K = [&](int buf, int kv0) {
        #pragma unroll
        for (int i = 0; i < 4; ++i) {
            int seg = wid * 4 + i;
            int r   = seg * 4 + (lane >> 4);
            int cb  = ((lane & 15) << 4) ^ ((r & 15) << 4);
            const char* g = KhB + (((size_t)(kv0 + r)) << 8) + cb;
            __builtin_amdgcn_global_load_lds(
                (const __attribute__((address_space(1))) void*)g,
                (__attribute__((address_space(3))) void*)(smem + buf * 16384 + seg * 1024),
                16, 0, 0);
        }
    };
    auto STAGE_V = [&](int buf, int kv0) {
        #pragma unroll
        for (int i = 0; i < 4; ++i) {
            int seg = wid * 4 + i;
            int rp  = seg * 4 + (lane >> 4);          // row-pair 0..63
            int q8  = (lane & 15) << 4;
            int pre = q8 ^ ((rp & 7) << 4);
            int r   = 2 * rp + (pre >> 7);            // VT d-row 0..127
            int cb  = pre & 127;
            const char* g = VThB + (size_t)r * (SEQ * 2) + ((size_t)kv0 << 1) + cb;
            __builtin_amdgcn_global_load_lds(
                (const __attribute__((address_space(1))) void*)g,
                (__attribute__((address_space(3))) void*)(smem + 32768 + buf * 16384 + seg * 1024),
                16, 0, 0);
        }
    };

// One pipeline phase for tile t:
//   vmcnt(4|0) -> barrier -> [stage K(t+2)] -> [QK^T(t+1) into SN] ->
//   softmax(SC) -> pack -> PV(V[t]) -> barrier -> [stage V(t+2)]
#define PHASE(SC0, SC1, SN0, SN1, KBUF, VBUF, DO_NEXT, DO_STG, SBUF, STILE) do {     \
    if (DO_NEXT) { asm volatile("s_waitcnt vmcnt(4)" ::: "memory"); }                \
    else         { asm volatile("s_waitcnt vmcnt(0)" ::: "memory"); }                \
    __builtin_amdgcn_s_barrier();                                                    \
    asm volatile("" ::: "memory");                                                   \
    if (DO_STG) STAGE_K(SBUF, (STILE) * KVB);                                        \
    if (DO_NEXT) {                                                                   \
        SN0 = (f32x16)(0.f); SN1 = (f32x16)(0.f);                                    \
        const char* krow0_ = (KBUF) + (size_t)l31 * 256;                             \
        const char* krow1_ = (KBUF) + (size_t)(32 + l31) * 256;                      \
        _Pragma("unroll")                                                            \
        for (int u = 0; u < 8; ++u) {                                                \
            int cb_ = (32 * u + 16 * hL) ^ swzK;                                     \
            bf16x8 k0_ = *(const bf16x8*)(krow0_ + cb_);                             \
            bf16x8 k1_ = *(const bf16x8*)(krow1_ + cb_);                             \
            SN0 = __builtin_amdgcn_mfma_f32_32x32x16_bf16(k0_, qf[u], SN0, 0, 0, 0); \
            SN1 = __builtin_amdgcn_mfma_f32_32x32x16_bf16(k1_, qf[u], SN1, 0, 0, 0); \
        }                                                                            \
    }                                                                                \
    {                                                                                \
        float smax_ = -1e30f;                                                        \
        _Pragma("unroll")                                                            \
        for (int r = 0; r < 16; ++r)                                                 \
            smax_ = fmaxf(smax_, fmaxf(SC0[r], SC1[r]));                             \
        smax_ = fmaxf(smax_, __shfl_xor(smax_, 32));                                 \
        if (!__all(smax_ - m_run <= 8.f)) {                                          \
            float mnew_ = fmaxf(m_run, smax_);                                       \
            float corr_ = __builtin_amdgcn_exp2f(m_run - mnew_);                     \
            _Pragma("unroll")                                                        \
            for (int m = 0; m < 4; ++m) acc[m] *= corr_;                             \
            l_run *= corr_;                                                          \
            m_run = mnew_;                                                           \
        }                                                                            \
        float psum_ = 0.f;                                                           \
        _Pragma("unroll")                                                            \
        for (int r = 0; r < 16; ++r) {                                               \
            SC0[r] = __builtin_amdgcn_exp2f(SC0[r] - m_run);                         \
            SC1[r] = __builtin_amdgcn_exp2f(SC1[r] - m_run);                         \
            psum_ += SC0[r] + SC1[r];                                                \
        }                                                                            \
        l_run += psum_;                                                              \
        uint32_t w0_[8], w1_[8];                                                     \
        _Pragma("unroll")                                                            \
        for (int k2 = 0; k2 < 8; ++k2) {                                             \
            w0_[k2] = packbf2(SC0[2 * k2], SC0[2 * k2 + 1]);                         \
            w1_[k2] = packbf2(SC1[2 * k2], SC1[2 * k2 + 1]);                         \
        }                                                                            \
        _Pragma("unroll")                                                            \
        for (int tj = 0; tj < 2; ++tj) {                                             \
            _Pragma("unroll")                                                        \
            for (int ssi = 0; ssi < 2; ++ssi) {                                      \
                uint32_t A0 = tj ? w1_[4 * ssi]     : w0_[4 * ssi];                  \
                uint32_t A1 = tj ? w1_[4 * ssi + 1] : w0_[4 * ssi + 1];              \
                uint32_t C0 = tj ? w1_[4 * ssi + 2] : w0_[4 * ssi + 2];              \
                uint32_t C1 = tj ? w1_[4 * ssi + 3] : w0_[4 * ssi + 3];              \
                uint32_t o0 = hL ? A0 : C0;                                          \
                uint32_t o1 = hL ? A1 : C1;                                          \
                uint32_t e0 = (uint32_t)__shfl_xor((int)o0, 32);                     \
                uint32_t e1 = (uint32_t)__shfl_xor((int)o1, 32);                     \
                union { uint32_t u[4]; bf16x8 v; } Bf;                               \
                Bf.u[0] = hL ? e0 : A0;                                              \
                Bf.u[1] = hL ? e1 : A1;                                              \
                Bf.u[2] = hL ? C0 : e0;                                              \
                Bf.u[3] = hL ? C1 : e1;                                              \
                const int cbv_ = (32 * (2 * tj + ssi) + 16 * hL) + ((l31 & 1) << 7); \
                _Pragma("unroll")                                                    \
                for (int m = 0; m < 4; ++m) {                                        \
                    int rp_ = 16 * m + (l31 >> 1);                                   \
                    bf16x8 vf_ = *(const bf16x8*)((VBUF) + (size_t)rp_ * 256 + (cbv_ ^ swzV)); \
                    acc[m] = __builtin_amdgcn_mfma_f32_32x32x16_bf16(vf_, Bf.v, acc[m], 0, 0, 0); \
                }                                                                    \
            }                                                                        \
        }                                                                            \
    }                                                                                \
    asm volatile("" ::: "memory");                                                   \
    __builtin_amdgcn_s_barrier();                                                    \
    if (DO_STG) STAGE_V(SBUF, (STILE) * KVB);                                        \
} while (0)

    const char* kb0 = smem;
    const char* kb1 = smem + 16384;
    const char* vb0 = smem + 32768;
    const char* vb1 = smem + 32768 + 16384;

    // ---- prologue: stage tiles 0,1 completely; full drain; compute S(0) ----
    STAGE_K(0, 0);
    STAGE_K(1, KVB);
    STAGE_V(0, 0);
    STAGE_V(1, KVB);
    asm volatile("s_waitcnt vmcnt(0)" ::: "memory");   // full drain (count-safe)
    __builtin_amdgcn_s_barrier();
    asm volatile("" ::: "memory");

    f32x16 sa0 = (f32x16)(0.f), sa1 = (f32x16)(0.f);
    f32x16 sb0, sb1;
    {
        const char* krow0 = kb0 + (size_t)l31 * 256;
        const char* krow1 = kb0 + (size_t)(32 + l31) * 256;
        #pragma unroll
        for (int u = 0; u < 8; ++u) {
            int cb = (32 * u + 16 * hL) ^ swzK;
            bf16x8 k0 = *(const bf16x8*)(krow0 + cb);
            bf16x8 k1 = *(const bf16x8*)(krow1 + cb);
            sa0 = __builtin_amdgcn_mfma_f32_32x32x16_bf16(k0, qf[u], sa0, 0, 0, 0);
            sa1 = __builtin_amdgcn_mfma_f32_32x32x16_bf16(k1, qf[u], sa1, 0, 0, 0);
        }
    }

    // ---- steady state: 2 tiles per iteration (compile-time buffer parity) ----
    #pragma unroll 1
    for (int tt = 0; tt < NT - 2; tt += 2) {
        PHASE(sa0, sa1, sb0, sb1, kb1, vb0, 1, 1, 0, tt + 2);   // tile tt
        PHASE(sb0, sb1, sa0, sa1, kb0, vb1, 1, 1, 1, tt + 3);   // tile tt+1
    }
    // ---- tail: tiles NT-2, NT-1 (no staging) ----
    PHASE(sa0, sa1, sb0, sb1, kb1, vb0, 1, 0, 0, 0);            // t = NT-2
    PHASE(sb0, sb1, sa0, sa1, kb0, vb1, 0, 0, 0, 0);            // t = NT-1

#undef PHASE

    // ---- epilogue: normalize, swizzled LDS transpose, coalesced stores ----
    __syncthreads();
    const float l_tot = l_run + __shfl_xor(l_run, 32);
    const float inv = 1.0f / l_tot;
    float* ob = (float*)(smem + wid * 16384);
    #pragma unroll
    for (int m = 0; m < 4; ++m) {
        #pragma unroll
        for (int r = 0; r < 16; ++r) {
            int d = 32 * m + (r & 3) + 8 * (r >> 2) + 4 * hL;
            ob[l31 * 128 + (d ^ ((l31 & 7) << 2))] = acc[m][r] * inv;
        }
    }
    __syncthreads();
    {
        float* outp = Out + ((size_t)head * SEQ + q0) * DIM;
        #pragma unroll
        for (int i = 0; i < 16; ++i) {
            int row = 2 * i + hL;
            f32x4 v = *(const f32x4*)(ob + row * 128 + ((4 * l31) ^ ((row & 7) << 2)));
            *(f32x4*)(outp + (size_t)row * DIM + 4 * l31) = v;
        }
    }
}

extern "C" void kernel_launch(void* const* d_in, const int* in_sizes, int n_in,
                              void* d_out, int out_size, void* d_ws, size_t ws_size,
                              hipStream_t stream) {
    (void)in_sizes; (void)n_in; (void)out_size;
    const float* q = (const float*)d_in[0];
    const float* k = (const float*)d_in[1];
    const float* v = (const float*)d_in[2];
    float* out = (float*)d_out;

    const size_t needed = (size_t)ELEMS * 2 * 3;
    if (ws_size < needed) return;

    unsigned short* qb = (unsigned short*)d_ws;
    unsigned short* kb = qb + ELEMS;
    unsigned short* vt = kb + ELEMS;

    prep<<<6144, 256, 0, stream>>>(q, k, v, qb, kb, vt);
    attn_fwd<<<512, 256, 0, stream>>>(qb, kb, vt, out);
}

// Round 9
// 217.759 us; speedup vs baseline: 1.0275x; 1.0041x over previous
//
#include <hip/hip_runtime.h>
#include <hip/hip_bf16.h>
#include <stdint.h>

#define BATCH 2
#define HEADS 16
#define BH    32
#define SEQ   2048
#define DIM   128
#define ELEMS (BATCH*HEADS*SEQ*DIM)   // 8388608 per tensor

#define KVB   32
#define NT    (SEQ/KVB)               // 64 tiles

using f32x4  = __attribute__((ext_vector_type(4))) float;
using f32x16 = __attribute__((ext_vector_type(16))) float;
using bf16x8 = __attribute__((ext_vector_type(8))) short;
using us4    = __attribute__((ext_vector_type(4))) unsigned short;
using ui2    = __attribute__((ext_vector_type(2))) unsigned int;

__device__ __forceinline__ unsigned short f2bf(float f) {
    union { float f; uint32_t u; } v; v.f = f;
    uint32_t u = v.u;
    uint32_t r = u + 0x7FFFu + ((u >> 16) & 1u);   // RNE
    return (unsigned short)(r >> 16);
}

__device__ __forceinline__ uint32_t packbf2(float lo, float hi) {
    __hip_bfloat162 h2 = __float22bfloat162_rn(make_float2(lo, hi));
    union { __hip_bfloat162 h; uint32_t u; } c; c.h = h2;
    return c.u;   // low16 = lo, high16 = hi
}

// ---- fused prep ----
// blocks [0,2048):    Q fp32 -> bf16, pre-scaled by 1/sqrt(d)*log2(e)
// blocks [2048,4096): K fp32 -> bf16
// blocks [4096,6144): V fp32 [bh][n][d] -> VT bf16 [bh][d][n]
__global__ __launch_bounds__(256) void prep(const float* __restrict__ Q,
                                            const float* __restrict__ K,
                                            const float* __restrict__ V,
                                            unsigned short* __restrict__ qb,
                                            unsigned short* __restrict__ kb,
                                            unsigned short* __restrict__ vt) {
    const int b = blockIdx.x, t = threadIdx.x;
    const float scl = 0.08838834764831845f * 1.4426950408889634f;
    if (b < 4096) {
        const bool isQ = b < 2048;
        const float* src = isQ ? Q : K;
        unsigned short* dst = isQ ? qb : kb;
        const float f = isQ ? scl : 1.0f;
        size_t base = (size_t)(isQ ? b : b - 2048) * 4096 + t * 4;
        #pragma unroll
        for (int j = 0; j < 4; ++j) {
            f32x4 v = *(const f32x4*)(src + base + j * 1024);
            us4 o;
            #pragma unroll
            for (int jj = 0; jj < 4; ++jj) o[jj] = f2bf(v[jj] * f);
            *(us4*)(dst + base + j * 1024) = o;
        }
    } else {
        __shared__ unsigned short tile[64][66];
        const int b2 = b - 4096;
        const int bh = b2 >> 6, rem = b2 & 63;
        const int n0 = (rem >> 1) * 64, d0 = (rem & 1) * 64;
        const int rr = t >> 4, cc = t & 15;
        #pragma unroll
        for (int j = 0; j < 4; ++j) {
            int row = rr + 16 * j;
            f32x4 v = *(const f32x4*)(V + ((size_t)bh * SEQ + n0 + row) * DIM + d0 + cc * 4);
            #pragma unroll
            for (int jj = 0; jj < 4; ++jj) tile[row][cc * 4 + jj] = f2bf(v[jj]);
        }
        __syncthreads();
        #pragma unroll
        for (int j = 0; j < 4; ++j) {
            int drow = rr + 16 * j;
            us4 o;
            #pragma unroll
            for (int jj = 0; jj < 4; ++jj) o[jj] = tile[cc * 4 + jj][drow];
            *(us4*)(vt + ((size_t)bh * DIM + d0 + drow) * SEQ + n0 + cc * 4) = o;
        }
    }
}

// ---- flash attention: 4 waves x QBLK=32, KVBLK=32, 32x32x16 MFMA ----
// LDS 32KB (K dbuf 2x8KB + VT dbuf 2x8KB) -> 3 blocks/CU (12 waves, +50% TLP
// vs the 64KB KVB=64 variant). r5 sync flow (r8 in-wave pipeline was null).
// PV B-frag redistribution via permlane32_swap (T12 primitive).
__global__ __launch_bounds__(256, 3) void attn_fwd(const unsigned short* __restrict__ Qb,
                                                   const unsigned short* __restrict__ Kb,
                                                   const unsigned short* __restrict__ VTb,
                                                   float* __restrict__ Out) {
    __shared__ __attribute__((aligned(16))) char smem[32768];

    const int bid  = blockIdx.x;
    const int xcd  = bid & 7;
    const int slot = bid >> 3;
    const int head = xcd * 4 + (slot >> 4);    // bijective: 512 = 8 XCD x 4 heads x 16 qtiles
    const int wid  = threadIdx.x >> 6;
    const int lane = threadIdx.x & 63;
    const int l31  = lane & 31;
    const int hL   = lane >> 5;
    const int q0   = (slot & 15) * 128 + wid * 32;

    const unsigned short* Qh = Qb + (size_t)head * SEQ * DIM;
    const char* KhB  = (const char*)(Kb  + (size_t)head * SEQ * DIM);
    const char* VThB = (const char*)(VTb + (size_t)head * DIM * SEQ);

    // Q B-frags (bf16, pre-scaled in prep): lane holds Q[q0+l31][16u + 8hL .. +7]
    bf16x8 qf[8];
    {
        const char* qrow = (const char*)(Qh + (size_t)(q0 + l31) * DIM) + 16 * hL;
        #pragma unroll
        for (int u = 0; u < 8; ++u) qf[u] = *(const bf16x8*)(qrow + 32 * u);
    }

    f32x16 acc[4];
    #pragma unroll
    for (int m = 0; m < 4; ++m) acc[m] = (f32x16)(0.f);
    float m_run = -INFINITY, l_run = 0.f;

    const int swzK = (l31 & 15) << 4;          // K read swizzle (16-slot over 256B rows)

    // stage one KV tile: K 8KB (32 rows x 256B) + VT 8KB (64 d-rowpairs x 128B);
    // 4 x global_load_lds(16B) per wave.
    auto STAGE = [&](int buf, int kv0) {
        #pragma unroll
        for (int i = 0; i < 2; ++i) {
            int seg = wid * 2 + i;                  // 0..7
            int r   = seg * 4 + (lane >> 4);        // K row 0..31
            int cb  = ((lane & 15) << 4) ^ ((r & 15) << 4);
            const char* g = KhB + (((size_t)(kv0 + r)) << 8) + cb;
            __builtin_amdgcn_global_load_lds(
                (const __attribute__((address_space(1))) void*)g,
                (__attribute__((address_space(3))) void*)(smem + buf * 8192 + seg * 1024),
                16, 0, 0);
        }
        #pragma unroll
        for (int i = 0; i < 2; ++i) {
            int seg = wid * 2 + i;                  // 0..7
            int rp  = seg * 8 + (lane >> 3);        // d-rowpair 0..63
            int c   = (lane & 7) << 4;              // 16B slot within 128B rowpair
            int pre = c ^ ((rp & 7) << 4);          // swizzle (bit6 = row-in-pair)
            int r   = 2 * rp + ((pre >> 6) & 1);    // VT d-row 0..127
            int cb  = pre & 63;
            const char* g = VThB + (size_t)r * (SEQ * 2) + ((size_t)kv0 << 1) + cb;
            __builtin_amdgcn_global_load_lds(
                (const __attribute__((address_space(1))) void*)g,
                (__attribute__((address_space(3))) void*)(smem + 16384 + buf * 8192 + seg * 1024),
                16, 0, 0);
        }
    };

    STAGE(0, 0);

    #pragma unroll 1
    for (int t = 0; t < NT; ++t) {
        const int cur = t & 1;
        if (t + 1 < NT) {
            STAGE(cur ^ 1, (t + 1) * KVB);
            asm volatile("s_waitcnt vmcnt(4)" ::: "memory");  // drain tile t; t+1 in flight
        } else {
            asm volatile("s_waitcnt vmcnt(0)" ::: "memory");
        }
        __builtin_amdgcn_s_barrier();
        asm volatile("" ::: "memory");

        const char* kb = smem + cur * 8192;
        const char* vb = smem + 16384 + cur * 8192;

        // ---- QK^T: S^T[kv][q], one 32x32 tile (scale pre-folded into Q) ----
        f32x16 s0 = (f32x16)(0.f);
        {
            const char* krow = kb + (size_t)l31 * 256;
            #pragma unroll
            for (int u = 0; u < 8; ++u) {
                int cb = (32 * u + 16 * hL) ^ swzK;
                bf16x8 k0 = *(const bf16x8*)(krow + cb);
                s0 = __builtin_amdgcn_mfma_f32_32x32x16_bf16(k0, qf[u], s0, 0, 0, 0);
            }
        }

        // ---- online softmax (16 scores/lane) ----
        float smax = -1e30f;
        #pragma unroll
        for (int r = 0; r < 16; ++r) smax = fmaxf(smax, s0[r]);
        smax = fmaxf(smax, __shfl_xor(smax, 32));

        if (!__all(smax - m_run <= 8.f)) {          // defer-max (T13)
            float mnew = fmaxf(m_run, smax);
            float corr = __builtin_amdgcn_exp2f(m_run - mnew);
            #pragma unroll
            for (int m = 0; m < 4; ++m) acc[m] *= corr;
            l_run *= corr;
            m_run = mnew;
        }

        float ps[4] = {0.f, 0.f, 0.f, 0.f};
        #pragma unroll
        for (int r = 0; r < 16; ++r) {
            s0[r] = __builtin_amdgcn_exp2f(s0[r] - m_run);
            ps[r & 3] += s0[r];
        }
        l_run += (ps[0] + ps[1]) + (ps[2] + ps[3]);  // lane-local; pair-reduced at end

        // ---- pack P to bf16 dword pairs ----
        uint32_t w0[8];
        #pragma unroll
        for (int k2 = 0; k2 < 8; ++k2)
            w0[k2] = packbf2(s0[2 * k2], s0[2 * k2 + 1]);

        // ---- PV: O^T[d][q] += V^T * P^T ; B-frag via permlane32_swap ----
        #pragma unroll
        for (int ss = 0; ss < 2; ++ss) {
            ui2 r02 = __builtin_amdgcn_permlane32_swap(w0[4 * ss],     w0[4 * ss + 2], false, false);
            ui2 r13 = __builtin_amdgcn_permlane32_swap(w0[4 * ss + 1], w0[4 * ss + 3], false, false);
            union { uint32_t u[4]; bf16x8 v; } Bf;
            Bf.u[0] = r02[0];
            Bf.u[1] = r13[0];
            Bf.u[2] = r02[1];
            Bf.u[3] = r13[1];
            #pragma unroll
            for (int m = 0; m < 4; ++m) {
                int rp = 16 * m + (l31 >> 1);
                int byte = ((((l31 & 1) << 6) | (32 * ss + 16 * hL)) ^ ((rp & 7) << 4));
                bf16x8 vf = *(const bf16x8*)(vb + (size_t)rp * 128 + byte);
                acc[m] = __builtin_amdgcn_mfma_f32_32x32x16_bf16(vf, Bf.v, acc[m], 0, 0, 0);
            }
        }

        asm volatile("" ::: "memory");
        __builtin_amdgcn_s_barrier();
    }

    // ---- epilogue: normalize; 2-pass per-wave LDS transpose (8KB/wave) ----
    __syncthreads();   // all waves done with K/V LDS
    const float l_tot = l_run + __shfl_xor(l_run, 32);
    const float inv = 1.0f / l_tot;
    float* ob = (float*)(smem + wid * 8192);   // 32 q-rows x 64 f32, XOR-swizzled
    #pragma unroll
    for (int h = 0; h < 2; ++h) {
        #pragma unroll
        for (int mm = 0; mm < 2; ++mm) {
            int m = 2 * h + mm;
            #pragma unroll
            for (int r = 0; r < 16; ++r) {
                int dl = 32 * mm + (r & 3) + 8 * (r >> 2) + 4 * hL;   // 0..63
                ob[l31 * 64 + (dl ^ ((l31 & 7) << 2))] = acc[m][r] * inv;
            }
        }
        __syncthreads();
        {
            int row = lane >> 1, ch = (lane & 1) * 32;
            float* dst = Out + ((size_t)head * SEQ + q0 + row) * DIM + 64 * h + ch;
            const float* src = ob + row * 64;
            #pragma unroll
            for (int j = 0; j < 8; ++j) {
                int col = ch + 4 * j;
                *(f32x4*)(dst + 4 * j) = *(const f32x4*)(src + (col ^ ((row & 7) << 2)));
            }
        }
        if (h == 0) __syncthreads();   // before overwriting ob
    }
}

extern "C" void kernel_launch(void* const* d_in, const int* in_sizes, int n_in,
                              void* d_out, int out_size, void* d_ws, size_t ws_size,
                              hipStream_t stream) {
    (void)in_sizes; (void)n_in; (void)out_size;
    const float* q = (const float*)d_in[0];
    const float* k = (const float*)d_in[1];
    const float* v = (const float*)d_in[2];
    float* out = (float*)d_out;

    const size_t needed = (size_t)ELEMS * 2 * 3;
    if (ws_size < needed) return;

    unsigned short* qb = (unsigned short*)d_ws;
    unsigned short* kb = qb + ELEMS;
    unsigned short* vt = kb + ELEMS;

    prep<<<6144, 256, 0, stream>>>(q, k, v, qb, kb, vt);
    attn_fwd<<<512, 256, 0, stream>>>(qb, kb, vt, out);
}